// Round 12
// baseline (2446.407 us; speedup 1.0000x reference)
//
#include <hip/hip_runtime.h>
#include <hip/hip_bf16.h>
#include <math.h>

// ---------------------------------------------------------------------------
// MoE round 12: (1) MODE0 -> BM=256 variant of the proven 2-barrier core
// (512 thr / 8 waves 4Mx2N, 48KB LDS, 3 blocks/CU): staged bytes/FLOP x0.75,
// B-panel refetch halves. (2) spart & Y intermediates in bf16 (halve MODE2/3
// write + combine read traffic). All else identical to R11.
// ---------------------------------------------------------------------------

#define T_TOK 4096
#define DHID 768
#define NE_R 32
#define NE_S 8
#define F_S 2304
#define F_R 1536
#define MAXROWS 20480   // 160 tiles * 128
#define MAX_TILES 160

typedef float f32x4 __attribute__((ext_vector_type(4)));
typedef short s16x8 __attribute__((ext_vector_type(8)));

__device__ __forceinline__ short f2bf(float f) {
  union { float f; unsigned u; } v; v.f = f;
  unsigned r = v.u + 0x7fffu + ((v.u >> 16) & 1u);   // RNE
  return (short)(r >> 16);
}
__device__ __forceinline__ float bf2f(short s) {
  union { unsigned u; float f; } v; v.u = ((unsigned)(unsigned short)s) << 16;
  return v.f;
}

// async global->LDS, 16B per lane, wave-uniform LDS base (per-lane global src OK)
#define GLD16(gsrc, ldst)                                                     \
  __builtin_amdgcn_global_load_lds(                                           \
      (const __attribute__((address_space(1))) void*)(gsrc),                  \
      (__attribute__((address_space(3))) void*)(ldst), 16, 0, 0)

// ---------------------------------------------------------------------------
// prep: x fp32->bf16 + fp32 router (one x read), + zero routing scratch.
__global__ __launch_bounds__(64) void prep_kernel(const float* __restrict__ x,
    short* __restrict__ xbf, const float* __restrict__ rdown,
    const float* __restrict__ rup, int* __restrict__ sel, float* __restrict__ w4,
    float* __restrict__ pent, int* __restrict__ tlist, float* __restrict__ wslot,
    int* __restrict__ cursor) {
  int t = blockIdx.x, lane = threadIdx.x;
  __shared__ float xs[DHID];
  __shared__ float xrs[64];
  __shared__ float lg[32];
  const float4* x4 = (const float4*)(x + (size_t)t * DHID);
  short4* o4 = (short4*)(xbf + (size_t)t * DHID);
#pragma unroll
  for (int i = 0; i < 3; ++i) {
    float4 v = x4[i * 64 + lane];
    ((float4*)xs)[i * 64 + lane] = v;
    short4 o;
    o.x = f2bf(v.x); o.y = f2bf(v.y); o.z = f2bf(v.z); o.w = f2bf(v.w);
    o4[i * 64 + lane] = o;
  }
  if (t < 80) {
    int base = t * 256 + lane * 4;
#pragma unroll
    for (int i = 0; i < 4; ++i) { tlist[base + i] = 0; wslot[base + i] = 0.f; }
  }
  if (t == 0 && lane < 32) cursor[lane] = 0;
  __syncthreads();
  float acc = 0.f;
#pragma unroll 8
  for (int d = 0; d < DHID; ++d) acc += xs[d] * rdown[d * 64 + lane];
  xrs[lane] = acc;
  __syncthreads();
  if (lane < 32) {
    float l = 0.f;
#pragma unroll 8
    for (int r = 0; r < 64; ++r) l += xrs[r] * rup[r * 32 + lane];
    lg[lane] = l;
  }
  __syncthreads();
  if (lane == 0) {
    int si[4]; float sv[4];
    unsigned taken = 0;
    for (int k = 0; k < 4; ++k) {            // top-4, ties -> lowest index
      float best = -3.4e38f; int bi = 0;
      for (int e = 0; e < 32; ++e)
        if (!((taken >> e) & 1u) && lg[e] > best) { best = lg[e]; bi = e; }
      taken |= 1u << bi; si[k] = bi; sv[k] = best;
    }
    float m = sv[0];
    float wv[4]; float zs = 0.f;
    for (int k = 0; k < 4; ++k) { wv[k] = __expf(sv[k] - m); zs += wv[k]; }
    for (int k = 0; k < 4; ++k) {
      sel[t * 4 + k] = si[k];
      w4[t * 4 + k] = wv[k] / zs;
    }
    float Z = 0.f;
    for (int e = 0; e < 32; ++e) Z += __expf(lg[e] - m);
    float ent = 0.f;
    for (int e = 0; e < 32; ++e) {
      float p = __expf(lg[e] - m) / Z;
      ent -= p * logf(p + 1e-10f);
    }
    pent[t] = ent;
  }
}

// slot assignment (value-deterministic); block-local histogram; block 0
// publishes meta[] and counts[].
__global__ __launch_bounds__(256) void build_kernel(const int* __restrict__ sel,
    const float* __restrict__ w4, int* __restrict__ counts,
    int* __restrict__ cursor, int* __restrict__ tlist, float* __restrict__ wslot,
    int* __restrict__ pos, int* __restrict__ meta) {
  __shared__ int hist[32];
  __shared__ int smeta[33];
  int tid = threadIdx.x;
  if (tid < 32) hist[tid] = 0;
  __syncthreads();
  for (int i = tid; i < T_TOK * 4; i += 256) atomicAdd(&hist[sel[i]], 1);
  __syncthreads();
  if (tid == 0) {
    int acc = 0;
    for (int e = 0; e < 32; ++e) { smeta[e] = acc; acc += (hist[e] + 127) >> 7; }
    smeta[32] = acc;
    if (blockIdx.x == 0) {
      for (int e = 0; e < 33; ++e) meta[e] = smeta[e];
      for (int e = 0; e < 32; ++e) counts[e] = hist[e];
    }
  }
  __syncthreads();
  int t = blockIdx.x * 256 + tid;
  if (t >= T_TOK) return;
#pragma unroll
  for (int k = 0; k < 4; ++k) {
    int e = sel[t * 4 + k];
    int slot = atomicAdd(&cursor[e], 1);
    int g = smeta[e] * 128 + slot;
    tlist[g] = t; wslot[g] = w4[t * 4 + k]; pos[t * 4 + k] = g;
  }
}

// ---------------------------------------------------------------------------
// 64x64-tile transpose+convert: out[c*ldo+r] (bf16) = in[r*C+c] (f32).
__device__ __forceinline__ void tile_transpose(const float* in, short* out,
                                               int R, int C, long ldo,
                                               int r0, int c0) {
  __shared__ float tile[64][65];
  int tx = threadIdx.x & 63, ty = threadIdx.x >> 6;  // 64 x 4
#pragma unroll
  for (int i = 0; i < 64; i += 4)
    tile[ty + i][tx] = in[(size_t)(r0 + ty + i) * C + (c0 + tx)];
  __syncthreads();
  int u = threadIdx.x & 15, v = threadIdx.x >> 4;    // 16 x 16
#pragma unroll
  for (int i = 0; i < 64; i += 16) {
    int c = v + i;
    short4 o;
    o.x = f2bf(tile[4 * u + 0][c]); o.y = f2bf(tile[4 * u + 1][c]);
    o.z = f2bf(tile[4 * u + 2][c]); o.w = f2bf(tile[4 * u + 3][c]);
    *(short4*)&out[(size_t)(c0 + c) * ldo + (r0 + 4 * u)] = o;
  }
}

// Shared-expert weight transposes (swg, swu, swd). Run before shared GEMMs.
__global__ __launch_bounds__(256) void transpose_shared(
    const float* __restrict__ swg, const float* __restrict__ swu,
    const float* __restrict__ swd, short* __restrict__ wgT,
    short* __restrict__ wuT, short* __restrict__ wdT) {
  int bid = blockIdx.x;
  const float* in; short* out; int R, C, nbx; long ldo;
  if (bid < 3456)      { in = swg; out = wgT; R = DHID; C = F_S; ldo = DHID; nbx = 36; }
  else if (bid < 6912) { bid -= 3456; in = swu; out = wuT; R = DHID; C = F_S; ldo = DHID; nbx = 36; }
  else                 { bid -= 6912; in = swd; out = wdT; R = F_S; C = DHID; ldo = F_S; nbx = 12; }
  int per = nbx * (R / 64);
  int b = bid / per, rem = bid % per;
  int c0 = (rem % nbx) * 64, r0 = (rem / nbx) * 64;
  tile_transpose(in + (size_t)b * R * C, out + (size_t)b * R * C, R, C, ldo, r0, c0);
}

// Routed-expert weight transposes (rw1, rw2). Run AFTER shared GEMMs
// (w1T/w2T overlap the then-dead wdT/Hsh arena regions).
__global__ __launch_bounds__(256) void transpose_routed(
    const float* __restrict__ rw1, const float* __restrict__ rw2,
    short* __restrict__ w1T, short* __restrict__ w2T) {
  int bid = blockIdx.x;
  const float* in; short* out; int R, C, nbx; long ldo;
  if (bid < 9216) { in = rw1; out = w1T; R = DHID; C = F_R; ldo = DHID; nbx = 24; }
  else            { bid -= 9216; in = rw2; out = w2T; R = F_R; C = DHID; ldo = F_R; nbx = 12; }
  int per = nbx * (R / 64);
  int b = bid / per, rem = bid % per;
  int c0 = (rem % nbx) * 64, r0 = (rem / nbx) * 64;
  tile_transpose(in + (size_t)b * R * C, out + (size_t)b * R * C, R, C, ldo, r0, c0);
}

// ---------------------------------------------------------------------------
// Shared GEMM1, BM=256 variant of the proven 2-barrier core. 512 thr = 8
// waves (4M x 2N), BK=64, 48KB LDS (3 blocks/CU). Bs: 64 gate rows + 64 up
// rows of the SAME f-cols; epilogue silu(g)*u -> bf16 Hsh. [+XCD N-swizzle]
__global__ __launch_bounds__(512, 6) void gemm_m0(
    const short* __restrict__ A, const short* __restrict__ Bg,
    const short* __restrict__ Bu, short* __restrict__ outH) {
  __shared__ short As[256 * 64];
  __shared__ short Bs[128 * 64];
  int tid = threadIdx.x;
  int wv = tid >> 6, lane = tid & 63;
  int wr = wv >> 1, wc = wv & 1;          // 4M x 2N
  int lrow = lane & 15, kg = lane >> 4;
  int lrow7 = lrow & 7;
  int e = blockIdx.z;

  int bx = blockIdx.x, by = blockIdx.y;   // gx=36, gy=16
  {
    int gx = gridDim.x, gy = gridDim.y;
    int nwg = gx * gy;                    // 576, %8==0
    int orig = by * gx + bx;
    int swz = (orig & 7) * (nwg >> 3) + (orig >> 3);
    bx = swz / gy; by = swz % gy;
  }
  int n0 = bx * 64;                       // 64 f-cols per block
  int m0 = by * 256;                      // 256 tokens per block

  int srow = tid >> 3;                              // 0..63
  int scol = ((tid & 7) ^ (srow & 7)) * 8;          // swizzled source chunk

  const short* asrc[4];
#pragma unroll
  for (int r = 0; r < 4; ++r)
    asrc[r] = A + (size_t)(m0 + r * 64 + srow) * DHID + scol;
  const short* bgsrc = Bg + (size_t)e * F_S * DHID + (size_t)(n0 + srow) * DHID + scol;
  const short* busrc = Bu + (size_t)e * F_S * DHID + (size_t)(n0 + srow) * DHID + scol;

  f32x4 acc[4][4] = {};

  for (int kt = 0; kt < DHID; kt += 64) {
    GLD16(asrc[0] + kt, As + (0 * 64 + wv * 8) * 64);
    GLD16(asrc[1] + kt, As + (1 * 64 + wv * 8) * 64);
    GLD16(asrc[2] + kt, As + (2 * 64 + wv * 8) * 64);
    GLD16(asrc[3] + kt, As + (3 * 64 + wv * 8) * 64);
    GLD16(bgsrc + kt, Bs + (0 * 64 + wv * 8) * 64);
    GLD16(busrc + kt, Bs + (1 * 64 + wv * 8) * 64);
    __syncthreads();
#pragma unroll
    for (int ks = 0; ks < 2; ++ks) {
      int pc = ((ks * 4 + kg) ^ lrow7) * 8;
      s16x8 af[4], bb[4];
#pragma unroll
      for (int i = 0; i < 4; ++i)
        af[i] = *(const s16x8*)&As[(wr * 64 + i * 16 + lrow) * 64 + pc];
#pragma unroll
      for (int j = 0; j < 4; ++j) {
        int brow = (j >= 2 ? 64 : 0) + wc * 32 + (j & 1) * 16 + lrow;
        bb[j] = *(const s16x8*)&Bs[brow * 64 + pc];
      }
#pragma unroll
      for (int i = 0; i < 4; ++i)
#pragma unroll
        for (int j = 0; j < 4; ++j)
          acc[i][j] = __builtin_amdgcn_mfma_f32_16x16x32_bf16(af[i], bb[j], acc[i][j], 0, 0, 0);
    }
    __syncthreads();
  }

  // epilogue: silu(gate)*up; C/D layout col=lane&15, row=(lane>>4)*4+r
  const long ldo = (long)NE_S * F_S;
#pragma unroll
  for (int i = 0; i < 4; ++i) {
#pragma unroll
    for (int r = 0; r < 4; ++r) {
      int row = m0 + wr * 64 + i * 16 + kg * 4 + r;
#pragma unroll
      for (int jp = 0; jp < 2; ++jp) {
        int col = n0 + wc * 32 + jp * 16 + lrow;
        float g = acc[i][jp][r];
        float u = acc[i][jp + 2][r];
        float h = g / (1.f + __expf(-g)) * u;
        outH[(size_t)row * ldo + (size_t)e * F_S + col] = f2bf(h);
      }
    }
  }
}

// ---------------------------------------------------------------------------
// Proven 2-barrier GEMM core for MODE 1/2/3 (bf16 outputs for 2/3 now).
// MODE 1: routed GEMM1 sparse gather, tanh-gelu*wslot -> Hr [+XCD tile-swizzle]
// MODE 2: shared GEMM2, 2 experts/block, bf16 spart       [+XCD N-swizzle]
// MODE 3: routed GEMM2 sparse, bf16 Y                     [+XCD tile-swizzle]
template<int MODE>
__global__ __launch_bounds__(256, 4) void gemm_k(
    const short* __restrict__ A, const short* __restrict__ B,
    short* __restrict__ outH, const float* __restrict__ wslot,
    const int* __restrict__ meta, const int* __restrict__ tlist,
    int K, int lda, long zbstride, long ldo, long orowz, long acolz) {
  constexpr int BM = 128;
  constexpr int WM = 64, FM = 4, FN = 4;
  __shared__ short As[BM * 64];
  __shared__ short Bs[128 * 64];

  int tid = threadIdx.x;
  int wv = tid >> 6, lane = tid & 63;
  int wr = wv >> 1, wc = wv & 1;
  int lrow = lane & 15, kg = lane >> 4;
  int lrow7 = lrow & 7;
  int z = blockIdx.z;

  int bx = blockIdx.x, by = blockIdx.y;
  {
    int gx = gridDim.x, gy = gridDim.y;
    int nwg = gx * gy;
    int orig = by * gx + bx;
    int swz = (orig & 7) * (nwg >> 3) + (orig >> 3);
    if constexpr (MODE == 2) {
      bx = swz / gy; by = swz % gy;      // XCD owns an N-slice
    } else {
      bx = swz % gx; by = swz / gx;      // XCD owns a tile-range
    }
  }
  int n0 = bx * 128;

  int eidx = z;
  int g0 = 0, m0 = by * BM;
  if constexpr (MODE == 1 || MODE == 3) {
    int total = meta[32];
    int ty = by;
    if (ty >= total) return;
    int e = 0;
    while (meta[e + 1] <= ty) ++e;    // <=32 uniform iters
    eidx = e;
    g0 = ty * BM;
  }

  int srow = tid >> 3;                             // 0..31
  int scol = ((tid & 7) ^ (srow & 7)) * 8;         // swizzled source chunk

  f32x4 acc[FM][FN] = {};

  constexpr int EPB = (MODE == 2) ? 2 : 1;
#pragma unroll 1
  for (int ei = 0; ei < EPB; ++ei) {
    int e = (MODE == 2) ? (z * 2 + ei) : eidx;
    const short* Bb = B + (size_t)e * zbstride + (size_t)n0 * K;

    const short *as0, *as1, *as2, *as3;
    {
      auto arow = [&](int row) -> const short* {
        if constexpr (MODE == 1) {
          return A + (size_t)tlist[g0 + row] * lda + scol;
        } else if constexpr (MODE == 2) {
          return A + ((size_t)(m0 + row)) * lda + (size_t)e * acolz + scol;
        } else {
          return A + ((size_t)(g0 + row)) * lda + scol;
        }
      };
      as0 = arow(srow); as1 = arow(32 + srow); as2 = arow(64 + srow); as3 = arow(96 + srow);
    }
    const short* bs0 = Bb + (size_t)srow * K + scol;
    const short* bs1 = bs0 + (size_t)32 * K;
    const short* bs2 = bs0 + (size_t)64 * K;
    const short* bs3 = bs0 + (size_t)96 * K;

    for (int kt = 0; kt < K; kt += 64) {
      GLD16(as0 + kt, As + (0 * 32 + wv * 8) * 64);
      GLD16(as1 + kt, As + (1 * 32 + wv * 8) * 64);
      GLD16(as2 + kt, As + (2 * 32 + wv * 8) * 64);
      GLD16(as3 + kt, As + (3 * 32 + wv * 8) * 64);
      GLD16(bs0 + kt, Bs + (0 * 32 + wv * 8) * 64);
      GLD16(bs1 + kt, Bs + (1 * 32 + wv * 8) * 64);
      GLD16(bs2 + kt, Bs + (2 * 32 + wv * 8) * 64);
      GLD16(bs3 + kt, Bs + (3 * 32 + wv * 8) * 64);
      __syncthreads();
#pragma unroll
      for (int ks = 0; ks < 2; ++ks) {
        int pc = ((ks * 4 + kg) ^ lrow7) * 8;
        s16x8 af[FM], bb[FN];
#pragma unroll
        for (int i = 0; i < FM; ++i)
          af[i] = *(const s16x8*)&As[(wr * WM + i * 16 + lrow) * 64 + pc];
#pragma unroll
        for (int j = 0; j < FN; ++j)
          bb[j] = *(const s16x8*)&Bs[(wc * 64 + j * 16 + lrow) * 64 + pc];
#pragma unroll
        for (int i = 0; i < FM; ++i)
#pragma unroll
          for (int j = 0; j < FN; ++j)
            acc[i][j] = __builtin_amdgcn_mfma_f32_16x16x32_bf16(af[i], bb[j], acc[i][j], 0, 0, 0);
      }
      __syncthreads();
    }
  }

  // epilogue: C/D layout col=lane&15, row=(lane>>4)*4+r
#pragma unroll
  for (int i = 0; i < FM; ++i) {
#pragma unroll
    for (int r = 0; r < 4; ++r) {
      int rl = wr * WM + i * 16 + kg * 4 + r;
      float wsc = 0.f;
      if constexpr (MODE == 1) wsc = wslot[g0 + rl];
#pragma unroll
      for (int j = 0; j < FN; ++j) {
        int col = n0 + wc * 64 + j * 16 + lrow;
        float v = acc[i][j][r];
        if constexpr (MODE == 1) {
          float vc = v * (0.7978845608f + 0.0356774081f * v * v);
          float h = v / (1.f + __expf(-2.f * vc)) * wsc;   // tanh-form GELU
          outH[(size_t)(g0 + rl) * ldo + col] = f2bf(h);
        } else if constexpr (MODE == 2) {
          outH[(size_t)z * orowz + (size_t)(m0 + rl) * DHID + col] = f2bf(v);
        } else if constexpr (MODE == 3) {
          outH[(size_t)(g0 + rl) * DHID + col] = f2bf(v);
        }
      }
    }
  }
}

// ---------------------------------------------------------------------------
// combine: out = mean(4 bf16 partials, each = 2 experts) + gather-sum of 4
// bf16 Y rows; per-token norms. 192 lanes x short4 (8B).
__global__ __launch_bounds__(256) void combine_kernel(const short* __restrict__ spart,
    const short* __restrict__ Y, const int* __restrict__ pos,
    float* __restrict__ out, float* __restrict__ pnorm) {
  int t = blockIdx.x, tid = threadIdx.x;
  int p0 = pos[t * 4], p1 = pos[t * 4 + 1], p2 = pos[t * 4 + 2], p3 = pos[t * 4 + 3];
  float s2 = 0.f, r2 = 0.f;
  if (tid < 192) {                                  // 768 / 4
    const short4* sp = (const short4*)spart;
    const short4* y4 = (const short4*)Y;
    size_t base = (size_t)t * 192 + tid;
    float sx = 0.f, sy = 0.f, sz = 0.f, sw = 0.f;
#pragma unroll
    for (int e = 0; e < 4; ++e) {
      short4 v = sp[(size_t)e * T_TOK * 192 + base];
      sx += bf2f(v.x); sy += bf2f(v.y); sz += bf2f(v.z); sw += bf2f(v.w);
    }
    sx *= 0.125f; sy *= 0.125f; sz *= 0.125f; sw *= 0.125f;
    float rx = 0.f, ry = 0.f, rz = 0.f, rw = 0.f;
    int pp[4] = {p0, p1, p2, p3};
#pragma unroll
    for (int k = 0; k < 4; ++k) {
      short4 v = y4[(size_t)pp[k] * 192 + tid];
      rx += bf2f(v.x); ry += bf2f(v.y); rz += bf2f(v.z); rw += bf2f(v.w);
    }
    float4 o;
    o.x = sx + rx; o.y = sy + ry; o.z = sz + rz; o.w = sw + rw;
    ((float4*)out)[base] = o;
    s2 = sx * sx + sy * sy + sz * sz + sw * sw;
    r2 = rx * rx + ry * ry + rz * rz + rw * rw;
  }
  for (int o = 32; o > 0; o >>= 1) { s2 += __shfl_down(s2, o); r2 += __shfl_down(r2, o); }
  __shared__ float red[8];
  int wv = tid >> 6, lane = tid & 63;
  if (lane == 0) { red[wv] = s2; red[4 + wv] = r2; }
  __syncthreads();
  if (tid == 0) {
    float st = red[0] + red[1] + red[2] + red[3];
    float rt = red[4] + red[5] + red[6] + red[7];
    pnorm[t] = sqrtf(st);
    pnorm[T_TOK + t] = sqrtf(rt);
  }
}

__global__ __launch_bounds__(256) void finalize_kernel(const int* __restrict__ counts,
    const float* __restrict__ pent, const float* __restrict__ pnorm, float* __restrict__ o) {
  int tid = threadIdx.x;
  float es = 0.f, ss = 0.f, rs = 0.f;
  for (int i = tid; i < T_TOK; i += 256) {
    es += pent[i]; ss += pnorm[i]; rs += pnorm[T_TOK + i];
  }
  float vs = 0.f;
  if (tid < 32) { float d = (float)counts[tid] - 512.f; vs = d * d; }
  for (int off = 32; off > 0; off >>= 1) {
    es += __shfl_down(es, off); ss += __shfl_down(ss, off);
    rs += __shfl_down(rs, off); vs += __shfl_down(vs, off);
  }
  __shared__ float red[16];
  int wv = tid >> 6, lane = tid & 63;
  if (lane == 0) { red[wv] = es; red[4 + wv] = ss; red[8 + wv] = rs; red[12 + wv] = vs; }
  __syncthreads();
  if (tid == 0) {
    es = red[0] + red[1] + red[2] + red[3];
    ss = red[4] + red[5] + red[6] + red[7];
    rs = red[8] + red[9] + red[10] + red[11];
    vs = red[12] + red[13] + red[14] + red[15];
    o[0] = vs / 31.f;                     // load_balance_loss (ddof=1, mean=512 exact)
    o[1] = es / (float)T_TOK;             // router_entropy
    o[2] = fabsf(ss - rs) / (float)T_TOK; // balance_loss
  }
}

// ---------------------------------------------------------------------------
extern "C" void kernel_launch(void* const* d_in, const int* in_sizes, int n_in,
                              void* d_out, int out_size, void* d_ws, size_t ws_size,
                              hipStream_t stream) {
  const float* x   = (const float*)d_in[0];
  const float* swg = (const float*)d_in[1];
  const float* swu = (const float*)d_in[2];
  const float* swd = (const float*)d_in[3];
  const float* rw1 = (const float*)d_in[4];
  const float* rw2 = (const float*)d_in[5];
  const float* rdn = (const float*)d_in[6];
  const float* rup = (const float*)d_in[7];
  float* fout = (float*)d_out;

  // ---- workspace layout ----
  char* w = (char*)d_ws;
  size_t off = 0;
  auto take = [&](size_t bytes) { char* p = w + off; off = (off + bytes + 255) & ~(size_t)255; return p; };
  short* xbf   = (short*)take((size_t)T_TOK * DHID * 2);
  int*   sel   = (int*)  take((size_t)T_TOK * 4 * 4);
  float* w4    = (float*)take((size_t)T_TOK * 4 * 4);
  int*   pos   = (int*)  take((size_t)T_TOK * 4 * 4);
  int*   counts= (int*)  take(32 * 4);
  int*   cursor= (int*)  take(32 * 4);
  int*   meta  = (int*)  take(64 * 4);
  int*   tlist = (int*)  take((size_t)MAXROWS * 4);
  float* wslot = (float*)take((size_t)MAXROWS * 4);
  float* pent  = (float*)take((size_t)T_TOK * 4);
  float* pnorm = (float*)take((size_t)2 * T_TOK * 4);
  short* spart = (short*)take((size_t)4 * T_TOK * DHID * 2);   // 25.2 MB (bf16)
  char*  arena = w + off;

  // arena (phase-overlapped; LIFETIME ORDER MATTERS):
  // shared phase:  [wgT 28.3][wuT 28.3][wdT 28.3][Hsh 151]
  // routed phase:  [Y 31.5][w1T 75.5][w2T 75.5][Hr 62.9]
  // transpose_routed (w1T,w2T) must run AFTER the shared GEMMs.
  short* wgT = (short*)arena;
  short* wuT = wgT + (size_t)NE_S * F_S * DHID;
  short* wdT = wuT + (size_t)NE_S * F_S * DHID;
  short* Hsh = wdT + (size_t)NE_S * F_S * DHID;
  short* Y   = (short*)arena;                               // bf16 now
  short* w1T = (short*)(arena + (size_t)MAXROWS * DHID * 2 + 256);
  short* w2T = w1T + (size_t)NE_R * F_R * DHID;
  short* Hr  = w2T + (size_t)NE_R * F_R * DHID;

  // ---- setup / router ----
  prep_kernel<<<T_TOK, 64, 0, stream>>>(x, xbf, rdn, rup, sel, w4, pent,
                                        tlist, wslot, cursor);
  build_kernel<<<T_TOK / 256, 256, 0, stream>>>(sel, w4, counts, cursor,
                                                tlist, wslot, pos, meta);

  // ---- shared experts ----
  transpose_shared<<<10368, 256, 0, stream>>>(swg, swu, swd, wgT, wuT, wdT);
  gemm_m0<<<dim3(F_S / 64, T_TOK / 256, NE_S), 512, 0, stream>>>(
      xbf, wgT, wuT, Hsh);
  gemm_k<2><<<dim3(DHID / 128, T_TOK / 128, NE_S / 2), 256, 0, stream>>>(
      Hsh, wdT, spart, nullptr, nullptr, nullptr,
      F_S, NE_S * F_S, (long)DHID * F_S, DHID, (long)T_TOK * DHID, (long)F_S);

  // ---- routed experts (sparse, tile-compacted) ----
  transpose_routed<<<18432, 256, 0, stream>>>(rw1, rw2, w1T, w2T);
  gemm_k<1><<<dim3(F_R / 128, MAX_TILES, 1), 256, 0, stream>>>(
      xbf, w1T, Hr, wslot, meta, tlist,
      DHID, DHID, (long)F_R * DHID, (long)F_R, 0, 0);
  gemm_k<3><<<dim3(DHID / 128, MAX_TILES, 1), 256, 0, stream>>>(
      Hr, w2T, Y, nullptr, meta, tlist,
      F_R, F_R, (long)DHID * F_R, DHID, 0, 0);

  // ---- combine + scalars ----
  combine_kernel<<<T_TOK, 256, 0, stream>>>(spart, Y, pos, fout, pnorm);
  finalize_kernel<<<1, 256, 0, stream>>>(counts, pent, pnorm, fout + (size_t)T_TOK * DHID);
}

// Round 13
// 903.956 us; speedup vs baseline: 2.7063x; 2.7063x over previous
//
#include <hip/hip_runtime.h>
#include <hip/hip_bf16.h>
#include <math.h>

// ---------------------------------------------------------------------------
// MoE round 13: fix R12's launch-bounds bug. __launch_bounds__(512, 6) capped
// VGPRs at ~85 < the ~104 needed -> acc spilled to scratch (VGPR=40, WRITE
// 5.7GB, 1914us). Correct arg: (512, 4) -> cap 128, 16 waves/CU (2 blocks x 8
// waves), same occupancy as R11 MODE0. BM=256 geometry itself verified (R12
// passed). bf16 spart/Y intermediates kept from R12.
// ---------------------------------------------------------------------------

#define T_TOK 4096
#define DHID 768
#define NE_R 32
#define NE_S 8
#define F_S 2304
#define F_R 1536
#define MAXROWS 20480   // 160 tiles * 128
#define MAX_TILES 160

typedef float f32x4 __attribute__((ext_vector_type(4)));
typedef short s16x8 __attribute__((ext_vector_type(8)));

__device__ __forceinline__ short f2bf(float f) {
  union { float f; unsigned u; } v; v.f = f;
  unsigned r = v.u + 0x7fffu + ((v.u >> 16) & 1u);   // RNE
  return (short)(r >> 16);
}
__device__ __forceinline__ float bf2f(short s) {
  union { unsigned u; float f; } v; v.u = ((unsigned)(unsigned short)s) << 16;
  return v.f;
}

// async global->LDS, 16B per lane, wave-uniform LDS base (per-lane global src OK)
#define GLD16(gsrc, ldst)                                                     \
  __builtin_amdgcn_global_load_lds(                                           \
      (const __attribute__((address_space(1))) void*)(gsrc),                  \
      (__attribute__((address_space(3))) void*)(ldst), 16, 0, 0)

// ---------------------------------------------------------------------------
// prep: x fp32->bf16 + fp32 router (one x read), + zero routing scratch.
__global__ __launch_bounds__(64) void prep_kernel(const float* __restrict__ x,
    short* __restrict__ xbf, const float* __restrict__ rdown,
    const float* __restrict__ rup, int* __restrict__ sel, float* __restrict__ w4,
    float* __restrict__ pent, int* __restrict__ tlist, float* __restrict__ wslot,
    int* __restrict__ cursor) {
  int t = blockIdx.x, lane = threadIdx.x;
  __shared__ float xs[DHID];
  __shared__ float xrs[64];
  __shared__ float lg[32];
  const float4* x4 = (const float4*)(x + (size_t)t * DHID);
  short4* o4 = (short4*)(xbf + (size_t)t * DHID);
#pragma unroll
  for (int i = 0; i < 3; ++i) {
    float4 v = x4[i * 64 + lane];
    ((float4*)xs)[i * 64 + lane] = v;
    short4 o;
    o.x = f2bf(v.x); o.y = f2bf(v.y); o.z = f2bf(v.z); o.w = f2bf(v.w);
    o4[i * 64 + lane] = o;
  }
  if (t < 80) {
    int base = t * 256 + lane * 4;
#pragma unroll
    for (int i = 0; i < 4; ++i) { tlist[base + i] = 0; wslot[base + i] = 0.f; }
  }
  if (t == 0 && lane < 32) cursor[lane] = 0;
  __syncthreads();
  float acc = 0.f;
#pragma unroll 8
  for (int d = 0; d < DHID; ++d) acc += xs[d] * rdown[d * 64 + lane];
  xrs[lane] = acc;
  __syncthreads();
  if (lane < 32) {
    float l = 0.f;
#pragma unroll 8
    for (int r = 0; r < 64; ++r) l += xrs[r] * rup[r * 32 + lane];
    lg[lane] = l;
  }
  __syncthreads();
  if (lane == 0) {
    int si[4]; float sv[4];
    unsigned taken = 0;
    for (int k = 0; k < 4; ++k) {            // top-4, ties -> lowest index
      float best = -3.4e38f; int bi = 0;
      for (int e = 0; e < 32; ++e)
        if (!((taken >> e) & 1u) && lg[e] > best) { best = lg[e]; bi = e; }
      taken |= 1u << bi; si[k] = bi; sv[k] = best;
    }
    float m = sv[0];
    float wv[4]; float zs = 0.f;
    for (int k = 0; k < 4; ++k) { wv[k] = __expf(sv[k] - m); zs += wv[k]; }
    for (int k = 0; k < 4; ++k) {
      sel[t * 4 + k] = si[k];
      w4[t * 4 + k] = wv[k] / zs;
    }
    float Z = 0.f;
    for (int e = 0; e < 32; ++e) Z += __expf(lg[e] - m);
    float ent = 0.f;
    for (int e = 0; e < 32; ++e) {
      float p = __expf(lg[e] - m) / Z;
      ent -= p * logf(p + 1e-10f);
    }
    pent[t] = ent;
  }
}

// slot assignment (value-deterministic); block-local histogram; block 0
// publishes meta[] and counts[].
__global__ __launch_bounds__(256) void build_kernel(const int* __restrict__ sel,
    const float* __restrict__ w4, int* __restrict__ counts,
    int* __restrict__ cursor, int* __restrict__ tlist, float* __restrict__ wslot,
    int* __restrict__ pos, int* __restrict__ meta) {
  __shared__ int hist[32];
  __shared__ int smeta[33];
  int tid = threadIdx.x;
  if (tid < 32) hist[tid] = 0;
  __syncthreads();
  for (int i = tid; i < T_TOK * 4; i += 256) atomicAdd(&hist[sel[i]], 1);
  __syncthreads();
  if (tid == 0) {
    int acc = 0;
    for (int e = 0; e < 32; ++e) { smeta[e] = acc; acc += (hist[e] + 127) >> 7; }
    smeta[32] = acc;
    if (blockIdx.x == 0) {
      for (int e = 0; e < 33; ++e) meta[e] = smeta[e];
      for (int e = 0; e < 32; ++e) counts[e] = hist[e];
    }
  }
  __syncthreads();
  int t = blockIdx.x * 256 + tid;
  if (t >= T_TOK) return;
#pragma unroll
  for (int k = 0; k < 4; ++k) {
    int e = sel[t * 4 + k];
    int slot = atomicAdd(&cursor[e], 1);
    int g = smeta[e] * 128 + slot;
    tlist[g] = t; wslot[g] = w4[t * 4 + k]; pos[t * 4 + k] = g;
  }
}

// ---------------------------------------------------------------------------
// 64x64-tile transpose+convert: out[c*ldo+r] (bf16) = in[r*C+c] (f32).
__device__ __forceinline__ void tile_transpose(const float* in, short* out,
                                               int R, int C, long ldo,
                                               int r0, int c0) {
  __shared__ float tile[64][65];
  int tx = threadIdx.x & 63, ty = threadIdx.x >> 6;  // 64 x 4
#pragma unroll
  for (int i = 0; i < 64; i += 4)
    tile[ty + i][tx] = in[(size_t)(r0 + ty + i) * C + (c0 + tx)];
  __syncthreads();
  int u = threadIdx.x & 15, v = threadIdx.x >> 4;    // 16 x 16
#pragma unroll
  for (int i = 0; i < 64; i += 16) {
    int c = v + i;
    short4 o;
    o.x = f2bf(tile[4 * u + 0][c]); o.y = f2bf(tile[4 * u + 1][c]);
    o.z = f2bf(tile[4 * u + 2][c]); o.w = f2bf(tile[4 * u + 3][c]);
    *(short4*)&out[(size_t)(c0 + c) * ldo + (r0 + 4 * u)] = o;
  }
}

// Shared-expert weight transposes (swg, swu, swd). Run before shared GEMMs.
__global__ __launch_bounds__(256) void transpose_shared(
    const float* __restrict__ swg, const float* __restrict__ swu,
    const float* __restrict__ swd, short* __restrict__ wgT,
    short* __restrict__ wuT, short* __restrict__ wdT) {
  int bid = blockIdx.x;
  const float* in; short* out; int R, C, nbx; long ldo;
  if (bid < 3456)      { in = swg; out = wgT; R = DHID; C = F_S; ldo = DHID; nbx = 36; }
  else if (bid < 6912) { bid -= 3456; in = swu; out = wuT; R = DHID; C = F_S; ldo = DHID; nbx = 36; }
  else                 { bid -= 6912; in = swd; out = wdT; R = F_S; C = DHID; ldo = F_S; nbx = 12; }
  int per = nbx * (R / 64);
  int b = bid / per, rem = bid % per;
  int c0 = (rem % nbx) * 64, r0 = (rem / nbx) * 64;
  tile_transpose(in + (size_t)b * R * C, out + (size_t)b * R * C, R, C, ldo, r0, c0);
}

// Routed-expert weight transposes (rw1, rw2). Run AFTER shared GEMMs
// (w1T/w2T overlap the then-dead wdT/Hsh arena regions).
__global__ __launch_bounds__(256) void transpose_routed(
    const float* __restrict__ rw1, const float* __restrict__ rw2,
    short* __restrict__ w1T, short* __restrict__ w2T) {
  int bid = blockIdx.x;
  const float* in; short* out; int R, C, nbx; long ldo;
  if (bid < 9216) { in = rw1; out = w1T; R = DHID; C = F_R; ldo = DHID; nbx = 24; }
  else            { bid -= 9216; in = rw2; out = w2T; R = F_R; C = DHID; ldo = F_R; nbx = 12; }
  int per = nbx * (R / 64);
  int b = bid / per, rem = bid % per;
  int c0 = (rem % nbx) * 64, r0 = (rem / nbx) * 64;
  tile_transpose(in + (size_t)b * R * C, out + (size_t)b * R * C, R, C, ldo, r0, c0);
}

// ---------------------------------------------------------------------------
// Shared GEMM1, BM=256 variant of the proven 2-barrier core. 512 thr = 8
// waves (4M x 2N), BK=64, 48KB LDS. __launch_bounds__(512, 4): VGPR cap 128
// (fits ~104; R12's (512,6) capped at ~85 -> acc spilled). 16 waves/CU.
// Bs: 64 gate rows + 64 up rows of the SAME f-cols; silu(g)*u -> bf16 Hsh.
__global__ __launch_bounds__(512, 4) void gemm_m0(
    const short* __restrict__ A, const short* __restrict__ Bg,
    const short* __restrict__ Bu, short* __restrict__ outH) {
  __shared__ short As[256 * 64];
  __shared__ short Bs[128 * 64];
  int tid = threadIdx.x;
  int wv = tid >> 6, lane = tid & 63;
  int wr = wv >> 1, wc = wv & 1;          // 4M x 2N
  int lrow = lane & 15, kg = lane >> 4;
  int lrow7 = lrow & 7;
  int e = blockIdx.z;

  int bx = blockIdx.x, by = blockIdx.y;   // gx=36, gy=16
  {
    int gx = gridDim.x, gy = gridDim.y;
    int nwg = gx * gy;                    // 576, %8==0
    int orig = by * gx + bx;
    int swz = (orig & 7) * (nwg >> 3) + (orig >> 3);
    bx = swz / gy; by = swz % gy;
  }
  int n0 = bx * 64;                       // 64 f-cols per block
  int m0 = by * 256;                      // 256 tokens per block

  int srow = tid >> 3;                              // 0..63
  int scol = ((tid & 7) ^ (srow & 7)) * 8;          // swizzled source chunk

  const short* asrc[4];
#pragma unroll
  for (int r = 0; r < 4; ++r)
    asrc[r] = A + (size_t)(m0 + r * 64 + srow) * DHID + scol;
  const short* bgsrc = Bg + (size_t)e * F_S * DHID + (size_t)(n0 + srow) * DHID + scol;
  const short* busrc = Bu + (size_t)e * F_S * DHID + (size_t)(n0 + srow) * DHID + scol;

  f32x4 acc[4][4] = {};

  for (int kt = 0; kt < DHID; kt += 64) {
    GLD16(asrc[0] + kt, As + (0 * 64 + wv * 8) * 64);
    GLD16(asrc[1] + kt, As + (1 * 64 + wv * 8) * 64);
    GLD16(asrc[2] + kt, As + (2 * 64 + wv * 8) * 64);
    GLD16(asrc[3] + kt, As + (3 * 64 + wv * 8) * 64);
    GLD16(bgsrc + kt, Bs + (0 * 64 + wv * 8) * 64);
    GLD16(busrc + kt, Bs + (1 * 64 + wv * 8) * 64);
    __syncthreads();
#pragma unroll
    for (int ks = 0; ks < 2; ++ks) {
      int pc = ((ks * 4 + kg) ^ lrow7) * 8;
      s16x8 af[4], bb[4];
#pragma unroll
      for (int i = 0; i < 4; ++i)
        af[i] = *(const s16x8*)&As[(wr * 64 + i * 16 + lrow) * 64 + pc];
#pragma unroll
      for (int j = 0; j < 4; ++j) {
        int brow = (j >= 2 ? 64 : 0) + wc * 32 + (j & 1) * 16 + lrow;
        bb[j] = *(const s16x8*)&Bs[brow * 64 + pc];
      }
#pragma unroll
      for (int i = 0; i < 4; ++i)
#pragma unroll
        for (int j = 0; j < 4; ++j)
          acc[i][j] = __builtin_amdgcn_mfma_f32_16x16x32_bf16(af[i], bb[j], acc[i][j], 0, 0, 0);
    }
    __syncthreads();
  }

  // epilogue: silu(gate)*up; C/D layout col=lane&15, row=(lane>>4)*4+r
  const long ldo = (long)NE_S * F_S;
#pragma unroll
  for (int i = 0; i < 4; ++i) {
#pragma unroll
    for (int r = 0; r < 4; ++r) {
      int row = m0 + wr * 64 + i * 16 + kg * 4 + r;
#pragma unroll
      for (int jp = 0; jp < 2; ++jp) {
        int col = n0 + wc * 32 + jp * 16 + lrow;
        float g = acc[i][jp][r];
        float u = acc[i][jp + 2][r];
        float h = g / (1.f + __expf(-g)) * u;
        outH[(size_t)row * ldo + (size_t)e * F_S + col] = f2bf(h);
      }
    }
  }
}

// ---------------------------------------------------------------------------
// Proven 2-barrier GEMM core for MODE 1/2/3 (bf16 outputs for 2/3).
// MODE 1: routed GEMM1 sparse gather, tanh-gelu*wslot -> Hr [+XCD tile-swizzle]
// MODE 2: shared GEMM2, 2 experts/block, bf16 spart       [+XCD N-swizzle]
// MODE 3: routed GEMM2 sparse, bf16 Y                     [+XCD tile-swizzle]
template<int MODE>
__global__ __launch_bounds__(256, 4) void gemm_k(
    const short* __restrict__ A, const short* __restrict__ B,
    short* __restrict__ outH, const float* __restrict__ wslot,
    const int* __restrict__ meta, const int* __restrict__ tlist,
    int K, int lda, long zbstride, long ldo, long orowz, long acolz) {
  constexpr int BM = 128;
  constexpr int WM = 64, FM = 4, FN = 4;
  __shared__ short As[BM * 64];
  __shared__ short Bs[128 * 64];

  int tid = threadIdx.x;
  int wv = tid >> 6, lane = tid & 63;
  int wr = wv >> 1, wc = wv & 1;
  int lrow = lane & 15, kg = lane >> 4;
  int lrow7 = lrow & 7;
  int z = blockIdx.z;

  int bx = blockIdx.x, by = blockIdx.y;
  {
    int gx = gridDim.x, gy = gridDim.y;
    int nwg = gx * gy;
    int orig = by * gx + bx;
    int swz = (orig & 7) * (nwg >> 3) + (orig >> 3);
    if constexpr (MODE == 2) {
      bx = swz / gy; by = swz % gy;      // XCD owns an N-slice
    } else {
      bx = swz % gx; by = swz / gx;      // XCD owns a tile-range
    }
  }
  int n0 = bx * 128;

  int eidx = z;
  int g0 = 0, m0 = by * BM;
  if constexpr (MODE == 1 || MODE == 3) {
    int total = meta[32];
    int ty = by;
    if (ty >= total) return;
    int e = 0;
    while (meta[e + 1] <= ty) ++e;    // <=32 uniform iters
    eidx = e;
    g0 = ty * BM;
  }

  int srow = tid >> 3;                             // 0..31
  int scol = ((tid & 7) ^ (srow & 7)) * 8;         // swizzled source chunk

  f32x4 acc[FM][FN] = {};

  constexpr int EPB = (MODE == 2) ? 2 : 1;
#pragma unroll 1
  for (int ei = 0; ei < EPB; ++ei) {
    int e = (MODE == 2) ? (z * 2 + ei) : eidx;
    const short* Bb = B + (size_t)e * zbstride + (size_t)n0 * K;

    const short *as0, *as1, *as2, *as3;
    {
      auto arow = [&](int row) -> const short* {
        if constexpr (MODE == 1) {
          return A + (size_t)tlist[g0 + row] * lda + scol;
        } else if constexpr (MODE == 2) {
          return A + ((size_t)(m0 + row)) * lda + (size_t)e * acolz + scol;
        } else {
          return A + ((size_t)(g0 + row)) * lda + scol;
        }
      };
      as0 = arow(srow); as1 = arow(32 + srow); as2 = arow(64 + srow); as3 = arow(96 + srow);
    }
    const short* bs0 = Bb + (size_t)srow * K + scol;
    const short* bs1 = bs0 + (size_t)32 * K;
    const short* bs2 = bs0 + (size_t)64 * K;
    const short* bs3 = bs0 + (size_t)96 * K;

    for (int kt = 0; kt < K; kt += 64) {
      GLD16(as0 + kt, As + (0 * 32 + wv * 8) * 64);
      GLD16(as1 + kt, As + (1 * 32 + wv * 8) * 64);
      GLD16(as2 + kt, As + (2 * 32 + wv * 8) * 64);
      GLD16(as3 + kt, As + (3 * 32 + wv * 8) * 64);
      GLD16(bs0 + kt, Bs + (0 * 32 + wv * 8) * 64);
      GLD16(bs1 + kt, Bs + (1 * 32 + wv * 8) * 64);
      GLD16(bs2 + kt, Bs + (2 * 32 + wv * 8) * 64);
      GLD16(bs3 + kt, Bs + (3 * 32 + wv * 8) * 64);
      __syncthreads();
#pragma unroll
      for (int ks = 0; ks < 2; ++ks) {
        int pc = ((ks * 4 + kg) ^ lrow7) * 8;
        s16x8 af[FM], bb[FN];
#pragma unroll
        for (int i = 0; i < FM; ++i)
          af[i] = *(const s16x8*)&As[(wr * WM + i * 16 + lrow) * 64 + pc];
#pragma unroll
        for (int j = 0; j < FN; ++j)
          bb[j] = *(const s16x8*)&Bs[(wc * 64 + j * 16 + lrow) * 64 + pc];
#pragma unroll
        for (int i = 0; i < FM; ++i)
#pragma unroll
          for (int j = 0; j < FN; ++j)
            acc[i][j] = __builtin_amdgcn_mfma_f32_16x16x32_bf16(af[i], bb[j], acc[i][j], 0, 0, 0);
      }
      __syncthreads();
    }
  }

  // epilogue: C/D layout col=lane&15, row=(lane>>4)*4+r
#pragma unroll
  for (int i = 0; i < FM; ++i) {
#pragma unroll
    for (int r = 0; r < 4; ++r) {
      int rl = wr * WM + i * 16 + kg * 4 + r;
      float wsc = 0.f;
      if constexpr (MODE == 1) wsc = wslot[g0 + rl];
#pragma unroll
      for (int j = 0; j < FN; ++j) {
        int col = n0 + wc * 64 + j * 16 + lrow;
        float v = acc[i][j][r];
        if constexpr (MODE == 1) {
          float vc = v * (0.7978845608f + 0.0356774081f * v * v);
          float h = v / (1.f + __expf(-2.f * vc)) * wsc;   // tanh-form GELU
          outH[(size_t)(g0 + rl) * ldo + col] = f2bf(h);
        } else if constexpr (MODE == 2) {
          outH[(size_t)z * orowz + (size_t)(m0 + rl) * DHID + col] = f2bf(v);
        } else if constexpr (MODE == 3) {
          outH[(size_t)(g0 + rl) * DHID + col] = f2bf(v);
        }
      }
    }
  }
}

// ---------------------------------------------------------------------------
// combine: out = mean(4 bf16 partials, each = 2 experts) + gather-sum of 4
// bf16 Y rows; per-token norms. 192 lanes x short4 (8B).
__global__ __launch_bounds__(256) void combine_kernel(const short* __restrict__ spart,
    const short* __restrict__ Y, const int* __restrict__ pos,
    float* __restrict__ out, float* __restrict__ pnorm) {
  int t = blockIdx.x, tid = threadIdx.x;
  int p0 = pos[t * 4], p1 = pos[t * 4 + 1], p2 = pos[t * 4 + 2], p3 = pos[t * 4 + 3];
  float s2 = 0.f, r2 = 0.f;
  if (tid < 192) {                                  // 768 / 4
    const short4* sp = (const short4*)spart;
    const short4* y4 = (const short4*)Y;
    size_t base = (size_t)t * 192 + tid;
    float sx = 0.f, sy = 0.f, sz = 0.f, sw = 0.f;
#pragma unroll
    for (int e = 0; e < 4; ++e) {
      short4 v = sp[(size_t)e * T_TOK * 192 + base];
      sx += bf2f(v.x); sy += bf2f(v.y); sz += bf2f(v.z); sw += bf2f(v.w);
    }
    sx *= 0.125f; sy *= 0.125f; sz *= 0.125f; sw *= 0.125f;
    float rx = 0.f, ry = 0.f, rz = 0.f, rw = 0.f;
    int pp[4] = {p0, p1, p2, p3};
#pragma unroll
    for (int k = 0; k < 4; ++k) {
      short4 v = y4[(size_t)pp[k] * 192 + tid];
      rx += bf2f(v.x); ry += bf2f(v.y); rz += bf2f(v.z); rw += bf2f(v.w);
    }
    float4 o;
    o.x = sx + rx; o.y = sy + ry; o.z = sz + rz; o.w = sw + rw;
    ((float4*)out)[base] = o;
    s2 = sx * sx + sy * sy + sz * sz + sw * sw;
    r2 = rx * rx + ry * ry + rz * rz + rw * rw;
  }
  for (int o = 32; o > 0; o >>= 1) { s2 += __shfl_down(s2, o); r2 += __shfl_down(r2, o); }
  __shared__ float red[8];
  int wv = tid >> 6, lane = tid & 63;
  if (lane == 0) { red[wv] = s2; red[4 + wv] = r2; }
  __syncthreads();
  if (tid == 0) {
    float st = red[0] + red[1] + red[2] + red[3];
    float rt = red[4] + red[5] + red[6] + red[7];
    pnorm[t] = sqrtf(st);
    pnorm[T_TOK + t] = sqrtf(rt);
  }
}

__global__ __launch_bounds__(256) void finalize_kernel(const int* __restrict__ counts,
    const float* __restrict__ pent, const float* __restrict__ pnorm, float* __restrict__ o) {
  int tid = threadIdx.x;
  float es = 0.f, ss = 0.f, rs = 0.f;
  for (int i = tid; i < T_TOK; i += 256) {
    es += pent[i]; ss += pnorm[i]; rs += pnorm[T_TOK + i];
  }
  float vs = 0.f;
  if (tid < 32) { float d = (float)counts[tid] - 512.f; vs = d * d; }
  for (int off = 32; off > 0; off >>= 1) {
    es += __shfl_down(es, off); ss += __shfl_down(ss, off);
    rs += __shfl_down(rs, off); vs += __shfl_down(vs, off);
  }
  __shared__ float red[16];
  int wv = tid >> 6, lane = tid & 63;
  if (lane == 0) { red[wv] = es; red[4 + wv] = ss; red[8 + wv] = rs; red[12 + wv] = vs; }
  __syncthreads();
  if (tid == 0) {
    es = red[0] + red[1] + red[2] + red[3];
    ss = red[4] + red[5] + red[6] + red[7];
    rs = red[8] + red[9] + red[10] + red[11];
    vs = red[12] + red[13] + red[14] + red[15];
    o[0] = vs / 31.f;                     // load_balance_loss (ddof=1, mean=512 exact)
    o[1] = es / (float)T_TOK;             // router_entropy
    o[2] = fabsf(ss - rs) / (float)T_TOK; // balance_loss
  }
}

// ---------------------------------------------------------------------------
extern "C" void kernel_launch(void* const* d_in, const int* in_sizes, int n_in,
                              void* d_out, int out_size, void* d_ws, size_t ws_size,
                              hipStream_t stream) {
  const float* x   = (const float*)d_in[0];
  const float* swg = (const float*)d_in[1];
  const float* swu = (const float*)d_in[2];
  const float* swd = (const float*)d_in[3];
  const float* rw1 = (const float*)d_in[4];
  const float* rw2 = (const float*)d_in[5];
  const float* rdn = (const float*)d_in[6];
  const float* rup = (const float*)d_in[7];
  float* fout = (float*)d_out;

  // ---- workspace layout ----
  char* w = (char*)d_ws;
  size_t off = 0;
  auto take = [&](size_t bytes) { char* p = w + off; off = (off + bytes + 255) & ~(size_t)255; return p; };
  short* xbf   = (short*)take((size_t)T_TOK * DHID * 2);
  int*   sel   = (int*)  take((size_t)T_TOK * 4 * 4);
  float* w4    = (float*)take((size_t)T_TOK * 4 * 4);
  int*   pos   = (int*)  take((size_t)T_TOK * 4 * 4);
  int*   counts= (int*)  take(32 * 4);
  int*   cursor= (int*)  take(32 * 4);
  int*   meta  = (int*)  take(64 * 4);
  int*   tlist = (int*)  take((size_t)MAXROWS * 4);
  float* wslot = (float*)take((size_t)MAXROWS * 4);
  float* pent  = (float*)take((size_t)T_TOK * 4);
  float* pnorm = (float*)take((size_t)2 * T_TOK * 4);
  short* spart = (short*)take((size_t)4 * T_TOK * DHID * 2);   // 25.2 MB (bf16)
  char*  arena = w + off;

  // arena (phase-overlapped; LIFETIME ORDER MATTERS):
  // shared phase:  [wgT 28.3][wuT 28.3][wdT 28.3][Hsh 151]
  // routed phase:  [Y 31.5][w1T 75.5][w2T 75.5][Hr 62.9]
  // transpose_routed (w1T,w2T) must run AFTER the shared GEMMs.
  short* wgT = (short*)arena;
  short* wuT = wgT + (size_t)NE_S * F_S * DHID;
  short* wdT = wuT + (size_t)NE_S * F_S * DHID;
  short* Hsh = wdT + (size_t)NE_S * F_S * DHID;
  short* Y   = (short*)arena;                               // bf16
  short* w1T = (short*)(arena + (size_t)MAXROWS * DHID * 2 + 256);
  short* w2T = w1T + (size_t)NE_R * F_R * DHID;
  short* Hr  = w2T + (size_t)NE_R * F_R * DHID;

  // ---- setup / router ----
  prep_kernel<<<T_TOK, 64, 0, stream>>>(x, xbf, rdn, rup, sel, w4, pent,
                                        tlist, wslot, cursor);
  build_kernel<<<T_TOK / 256, 256, 0, stream>>>(sel, w4, counts, cursor,
                                                tlist, wslot, pos, meta);

  // ---- shared experts ----
  transpose_shared<<<10368, 256, 0, stream>>>(swg, swu, swd, wgT, wuT, wdT);
  gemm_m0<<<dim3(F_S / 64, T_TOK / 256, NE_S), 512, 0, stream>>>(
      xbf, wgT, wuT, Hsh);
  gemm_k<2><<<dim3(DHID / 128, T_TOK / 128, NE_S / 2), 256, 0, stream>>>(
      Hsh, wdT, spart, nullptr, nullptr, nullptr,
      F_S, NE_S * F_S, (long)DHID * F_S, DHID, (long)T_TOK * DHID, (long)F_S);

  // ---- routed experts (sparse, tile-compacted) ----
  transpose_routed<<<18432, 256, 0, stream>>>(rw1, rw2, w1T, w2T);
  gemm_k<1><<<dim3(F_R / 128, MAX_TILES, 1), 256, 0, stream>>>(
      xbf, w1T, Hr, wslot, meta, tlist,
      DHID, DHID, (long)F_R * DHID, (long)F_R, 0, 0);
  gemm_k<3><<<dim3(DHID / 128, MAX_TILES, 1), 256, 0, stream>>>(
      Hr, w2T, Y, nullptr, meta, tlist,
      F_R, F_R, (long)DHID * F_R, DHID, 0, 0);

  // ---- combine + scalars ----
  combine_kernel<<<T_TOK, 256, 0, stream>>>(spart, Y, pos, fout, pnorm);
  finalize_kernel<<<1, 256, 0, stream>>>(counts, pent, pnorm, fout + (size_t)T_TOK * DHID);
}

// Round 14
// 787.085 us; speedup vs baseline: 3.1082x; 1.1485x over previous
//
#include <hip/hip_runtime.h>
#include <hip/hip_bf16.h>
#include <math.h>

// ---------------------------------------------------------------------------
// MoE round 14: merge of verified states. MODE0 = R11's dual-B 2-barrier core
// (BM=128, 4 waves, 250us, zero spill -- BM=256/512thr spills: 64-arch-VGPR
// partition < ~75 needed, R12/R13 evidence). bf16 spart/Y intermediates kept
// from R13 (~50us verified win). prep/build/combine unchanged from R13.
// ---------------------------------------------------------------------------

#define T_TOK 4096
#define DHID 768
#define NE_R 32
#define NE_S 8
#define F_S 2304
#define F_R 1536
#define MAXROWS 20480   // 160 tiles * 128
#define MAX_TILES 160

typedef float f32x4 __attribute__((ext_vector_type(4)));
typedef short s16x8 __attribute__((ext_vector_type(8)));

__device__ __forceinline__ short f2bf(float f) {
  union { float f; unsigned u; } v; v.f = f;
  unsigned r = v.u + 0x7fffu + ((v.u >> 16) & 1u);   // RNE
  return (short)(r >> 16);
}
__device__ __forceinline__ float bf2f(short s) {
  union { unsigned u; float f; } v; v.u = ((unsigned)(unsigned short)s) << 16;
  return v.f;
}

// async global->LDS, 16B per lane, wave-uniform LDS base (per-lane global src OK)
#define GLD16(gsrc, ldst)                                                     \
  __builtin_amdgcn_global_load_lds(                                           \
      (const __attribute__((address_space(1))) void*)(gsrc),                  \
      (__attribute__((address_space(3))) void*)(ldst), 16, 0, 0)

// ---------------------------------------------------------------------------
// prep: x fp32->bf16 + fp32 router (one x read), + zero routing scratch.
__global__ __launch_bounds__(64) void prep_kernel(const float* __restrict__ x,
    short* __restrict__ xbf, const float* __restrict__ rdown,
    const float* __restrict__ rup, int* __restrict__ sel, float* __restrict__ w4,
    float* __restrict__ pent, int* __restrict__ tlist, float* __restrict__ wslot,
    int* __restrict__ cursor) {
  int t = blockIdx.x, lane = threadIdx.x;
  __shared__ float xs[DHID];
  __shared__ float xrs[64];
  __shared__ float lg[32];
  const float4* x4 = (const float4*)(x + (size_t)t * DHID);
  short4* o4 = (short4*)(xbf + (size_t)t * DHID);
#pragma unroll
  for (int i = 0; i < 3; ++i) {
    float4 v = x4[i * 64 + lane];
    ((float4*)xs)[i * 64 + lane] = v;
    short4 o;
    o.x = f2bf(v.x); o.y = f2bf(v.y); o.z = f2bf(v.z); o.w = f2bf(v.w);
    o4[i * 64 + lane] = o;
  }
  if (t < 80) {
    int base = t * 256 + lane * 4;
#pragma unroll
    for (int i = 0; i < 4; ++i) { tlist[base + i] = 0; wslot[base + i] = 0.f; }
  }
  if (t == 0 && lane < 32) cursor[lane] = 0;
  __syncthreads();
  float acc = 0.f;
#pragma unroll 8
  for (int d = 0; d < DHID; ++d) acc += xs[d] * rdown[d * 64 + lane];
  xrs[lane] = acc;
  __syncthreads();
  if (lane < 32) {
    float l = 0.f;
#pragma unroll 8
    for (int r = 0; r < 64; ++r) l += xrs[r] * rup[r * 32 + lane];
    lg[lane] = l;
  }
  __syncthreads();
  if (lane == 0) {
    int si[4]; float sv[4];
    unsigned taken = 0;
    for (int k = 0; k < 4; ++k) {            // top-4, ties -> lowest index
      float best = -3.4e38f; int bi = 0;
      for (int e = 0; e < 32; ++e)
        if (!((taken >> e) & 1u) && lg[e] > best) { best = lg[e]; bi = e; }
      taken |= 1u << bi; si[k] = bi; sv[k] = best;
    }
    float m = sv[0];
    float wv[4]; float zs = 0.f;
    for (int k = 0; k < 4; ++k) { wv[k] = __expf(sv[k] - m); zs += wv[k]; }
    for (int k = 0; k < 4; ++k) {
      sel[t * 4 + k] = si[k];
      w4[t * 4 + k] = wv[k] / zs;
    }
    float Z = 0.f;
    for (int e = 0; e < 32; ++e) Z += __expf(lg[e] - m);
    float ent = 0.f;
    for (int e = 0; e < 32; ++e) {
      float p = __expf(lg[e] - m) / Z;
      ent -= p * logf(p + 1e-10f);
    }
    pent[t] = ent;
  }
}

// slot assignment (value-deterministic); block-local histogram; block 0
// publishes meta[] and counts[].
__global__ __launch_bounds__(256) void build_kernel(const int* __restrict__ sel,
    const float* __restrict__ w4, int* __restrict__ counts,
    int* __restrict__ cursor, int* __restrict__ tlist, float* __restrict__ wslot,
    int* __restrict__ pos, int* __restrict__ meta) {
  __shared__ int hist[32];
  __shared__ int smeta[33];
  int tid = threadIdx.x;
  if (tid < 32) hist[tid] = 0;
  __syncthreads();
  for (int i = tid; i < T_TOK * 4; i += 256) atomicAdd(&hist[sel[i]], 1);
  __syncthreads();
  if (tid == 0) {
    int acc = 0;
    for (int e = 0; e < 32; ++e) { smeta[e] = acc; acc += (hist[e] + 127) >> 7; }
    smeta[32] = acc;
    if (blockIdx.x == 0) {
      for (int e = 0; e < 33; ++e) meta[e] = smeta[e];
      for (int e = 0; e < 32; ++e) counts[e] = hist[e];
    }
  }
  __syncthreads();
  int t = blockIdx.x * 256 + tid;
  if (t >= T_TOK) return;
#pragma unroll
  for (int k = 0; k < 4; ++k) {
    int e = sel[t * 4 + k];
    int slot = atomicAdd(&cursor[e], 1);
    int g = smeta[e] * 128 + slot;
    tlist[g] = t; wslot[g] = w4[t * 4 + k]; pos[t * 4 + k] = g;
  }
}

// ---------------------------------------------------------------------------
// 64x64-tile transpose+convert: out[c*ldo+r] (bf16) = in[r*C+c] (f32).
__device__ __forceinline__ void tile_transpose(const float* in, short* out,
                                               int R, int C, long ldo,
                                               int r0, int c0) {
  __shared__ float tile[64][65];
  int tx = threadIdx.x & 63, ty = threadIdx.x >> 6;  // 64 x 4
#pragma unroll
  for (int i = 0; i < 64; i += 4)
    tile[ty + i][tx] = in[(size_t)(r0 + ty + i) * C + (c0 + tx)];
  __syncthreads();
  int u = threadIdx.x & 15, v = threadIdx.x >> 4;    // 16 x 16
#pragma unroll
  for (int i = 0; i < 64; i += 16) {
    int c = v + i;
    short4 o;
    o.x = f2bf(tile[4 * u + 0][c]); o.y = f2bf(tile[4 * u + 1][c]);
    o.z = f2bf(tile[4 * u + 2][c]); o.w = f2bf(tile[4 * u + 3][c]);
    *(short4*)&out[(size_t)(c0 + c) * ldo + (r0 + 4 * u)] = o;
  }
}

// Shared-expert weight transposes (swg, swu, swd). Run before shared GEMMs.
__global__ __launch_bounds__(256) void transpose_shared(
    const float* __restrict__ swg, const float* __restrict__ swu,
    const float* __restrict__ swd, short* __restrict__ wgT,
    short* __restrict__ wuT, short* __restrict__ wdT) {
  int bid = blockIdx.x;
  const float* in; short* out; int R, C, nbx; long ldo;
  if (bid < 3456)      { in = swg; out = wgT; R = DHID; C = F_S; ldo = DHID; nbx = 36; }
  else if (bid < 6912) { bid -= 3456; in = swu; out = wuT; R = DHID; C = F_S; ldo = DHID; nbx = 36; }
  else                 { bid -= 6912; in = swd; out = wdT; R = F_S; C = DHID; ldo = F_S; nbx = 12; }
  int per = nbx * (R / 64);
  int b = bid / per, rem = bid % per;
  int c0 = (rem % nbx) * 64, r0 = (rem / nbx) * 64;
  tile_transpose(in + (size_t)b * R * C, out + (size_t)b * R * C, R, C, ldo, r0, c0);
}

// Routed-expert weight transposes (rw1, rw2). Run AFTER shared GEMMs
// (w1T/w2T overlap the then-dead wdT/Hsh arena regions).
__global__ __launch_bounds__(256) void transpose_routed(
    const float* __restrict__ rw1, const float* __restrict__ rw2,
    short* __restrict__ w1T, short* __restrict__ w2T) {
  int bid = blockIdx.x;
  const float* in; short* out; int R, C, nbx; long ldo;
  if (bid < 9216) { in = rw1; out = w1T; R = DHID; C = F_R; ldo = DHID; nbx = 24; }
  else            { bid -= 9216; in = rw2; out = w2T; R = F_R; C = DHID; ldo = F_R; nbx = 12; }
  int per = nbx * (R / 64);
  int b = bid / per, rem = bid % per;
  int c0 = (rem % nbx) * 64, r0 = (rem / nbx) * 64;
  tile_transpose(in + (size_t)b * R * C, out + (size_t)b * R * C, R, C, ldo, r0, c0);
}

// ---------------------------------------------------------------------------
// bf16 MFMA GEMM, BM=128, BK=64, 4 waves, v_mfma_f32_16x16x32_bf16,
// XOR-swizzled LDS (phys chunk = logical ^ (row&7), pre-swizzled global src).
// MODE 0: shared GEMM1 paired gate/up (Bs rows 0-63 = wgT cols, 64-127 = wuT
//         same cols), silu(g)*u -> bf16 Hsh.               [+XCD N-swizzle]
// MODE 1: routed GEMM1 sparse gather, tanh-gelu*wslot -> Hr [+XCD tile-swizzle]
// MODE 2: shared GEMM2, 2 experts/block, bf16 spart        [+XCD N-swizzle]
// MODE 3: routed GEMM2 sparse, bf16 Y                      [+XCD tile-swizzle]
template<int MODE>
__global__ __launch_bounds__(256, 4) void gemm_k(
    const short* __restrict__ A, const short* __restrict__ B,
    const short* __restrict__ B2, short* __restrict__ outH,
    const float* __restrict__ wslot, const int* __restrict__ meta,
    const int* __restrict__ tlist,
    int K, int lda, long zbstride, long ldo, long orowz, long acolz) {
  constexpr int BM = 128;
  constexpr int WM = 64, FM = 4, FN = 4;
  __shared__ short As[BM * 64];
  __shared__ short Bs[128 * 64];

  int tid = threadIdx.x;
  int wv = tid >> 6, lane = tid & 63;
  int wr = wv >> 1, wc = wv & 1;
  int lrow = lane & 15, kg = lane >> 4;
  int lrow7 = lrow & 7;
  int z = blockIdx.z;

  int bx = blockIdx.x, by = blockIdx.y;
  {
    int gx = gridDim.x, gy = gridDim.y;
    int nwg = gx * gy;
    int orig = by * gx + bx;
    int swz = (orig & 7) * (nwg >> 3) + (orig >> 3);
    if constexpr (MODE == 0 || MODE == 2) {
      bx = swz / gy; by = swz % gy;      // XCD owns an N-slice (B-panel hot)
    } else {
      bx = swz % gx; by = swz / gx;      // XCD owns a tile-range
    }
  }
  int n0 = bx * ((MODE == 0) ? 64 : 128);

  int eidx = z;
  int g0 = 0, m0 = by * BM;
  if constexpr (MODE == 1 || MODE == 3) {
    int total = meta[32];
    int ty = by;
    if (ty >= total) return;
    int e = 0;
    while (meta[e + 1] <= ty) ++e;    // <=32 uniform iters
    eidx = e;
    g0 = ty * BM;
  }

  int srow = tid >> 3;                             // 0..31
  int scol = ((tid & 7) ^ (srow & 7)) * 8;         // swizzled source chunk

  f32x4 acc[FM][FN] = {};

  constexpr int EPB = (MODE == 2) ? 2 : 1;
#pragma unroll 1
  for (int ei = 0; ei < EPB; ++ei) {
    int e = (MODE == 2) ? (z * 2 + ei) : eidx;
    const short* Bb = B + (size_t)e * zbstride + (size_t)n0 * K;

    const short *as0, *as1, *as2, *as3;
    {
      auto arow = [&](int row) -> const short* {
        if constexpr (MODE == 1) {
          return A + (size_t)tlist[g0 + row] * lda + scol;
        } else if constexpr (MODE == 2) {
          return A + ((size_t)(m0 + row)) * lda + (size_t)e * acolz + scol;
        } else if constexpr (MODE == 3) {
          return A + ((size_t)(g0 + row)) * lda + scol;
        } else {
          return A + ((size_t)(m0 + row)) * lda + scol;
        }
      };
      as0 = arow(srow); as1 = arow(32 + srow); as2 = arow(64 + srow); as3 = arow(96 + srow);
    }
    const short* bs0 = Bb + (size_t)srow * K + scol;
    const short* bs1 = bs0 + (size_t)32 * K;
    const short* bs2;
    const short* bs3;
    if constexpr (MODE == 0) {
      // Bs rows 64-127 <- wuT (up-projection), same n-columns as gate
      const short* B2b = B2 + (size_t)z * zbstride + (size_t)n0 * K;
      bs2 = B2b + (size_t)srow * K + scol;
      bs3 = bs2 + (size_t)32 * K;
    } else {
      bs2 = bs0 + (size_t)64 * K;
      bs3 = bs0 + (size_t)96 * K;
    }

    for (int kt = 0; kt < K; kt += 64) {
      GLD16(as0 + kt, As + (0 * 32 + wv * 8) * 64);
      GLD16(as1 + kt, As + (1 * 32 + wv * 8) * 64);
      GLD16(as2 + kt, As + (2 * 32 + wv * 8) * 64);
      GLD16(as3 + kt, As + (3 * 32 + wv * 8) * 64);
      GLD16(bs0 + kt, Bs + (0 * 32 + wv * 8) * 64);
      GLD16(bs1 + kt, Bs + (1 * 32 + wv * 8) * 64);
      GLD16(bs2 + kt, Bs + (2 * 32 + wv * 8) * 64);
      GLD16(bs3 + kt, Bs + (3 * 32 + wv * 8) * 64);
      __syncthreads();
#pragma unroll
      for (int ks = 0; ks < 2; ++ks) {
        int pc = ((ks * 4 + kg) ^ lrow7) * 8;        // swizzled chunk
        s16x8 af[FM], bb[FN];
#pragma unroll
        for (int i = 0; i < FM; ++i)
          af[i] = *(const s16x8*)&As[(wr * WM + i * 16 + lrow) * 64 + pc];
#pragma unroll
        for (int j = 0; j < FN; ++j) {
          int brow;
          if constexpr (MODE == 0)
            brow = (j >= 2 ? 64 : 0) + wc * 32 + (j & 1) * 16 + lrow;
          else
            brow = wc * 64 + j * 16 + lrow;
          bb[j] = *(const s16x8*)&Bs[brow * 64 + pc];
        }
#pragma unroll
        for (int i = 0; i < FM; ++i)
#pragma unroll
          for (int j = 0; j < FN; ++j)
            acc[i][j] = __builtin_amdgcn_mfma_f32_16x16x32_bf16(af[i], bb[j], acc[i][j], 0, 0, 0);
      }
      __syncthreads();
    }
  }

  // epilogue: C/D layout col=lane&15, row=(lane>>4)*4+r  [verified m89]
#pragma unroll
  for (int i = 0; i < FM; ++i) {
#pragma unroll
    for (int r = 0; r < 4; ++r) {
      int rl = wr * WM + i * 16 + kg * 4 + r;
      float wsc = 0.f;
      if constexpr (MODE == 1) wsc = wslot[g0 + rl];
      if constexpr (MODE == 0) {
#pragma unroll
        for (int jp = 0; jp < 2; ++jp) {
          int col = n0 + wc * 32 + jp * 16 + lrow;
          float g = acc[i][jp][r];
          float u = acc[i][jp + 2][r];
          float h = g / (1.f + __expf(-g)) * u;                      // silu(g)*u
          outH[(size_t)(m0 + rl) * ldo + (size_t)z * F_S + col] = f2bf(h);
        }
      } else {
#pragma unroll
        for (int j = 0; j < FN; ++j) {
          int col = n0 + wc * 64 + j * 16 + lrow;
          float v = acc[i][j][r];
          if constexpr (MODE == 1) {
            float vc = v * (0.7978845608f + 0.0356774081f * v * v);
            float h = v / (1.f + __expf(-2.f * vc)) * wsc;   // tanh-form GELU
            outH[(size_t)(g0 + rl) * ldo + col] = f2bf(h);
          } else if constexpr (MODE == 2) {
            outH[(size_t)z * orowz + (size_t)(m0 + rl) * DHID + col] = f2bf(v);
          } else if constexpr (MODE == 3) {
            outH[(size_t)(g0 + rl) * DHID + col] = f2bf(v);
          }
        }
      }
    }
  }
}

// ---------------------------------------------------------------------------
// combine: out = mean(4 bf16 partials, each = 2 experts) + gather-sum of 4
// bf16 Y rows; per-token norms. 192 lanes x short4 (8B).
__global__ __launch_bounds__(256) void combine_kernel(const short* __restrict__ spart,
    const short* __restrict__ Y, const int* __restrict__ pos,
    float* __restrict__ out, float* __restrict__ pnorm) {
  int t = blockIdx.x, tid = threadIdx.x;
  int p0 = pos[t * 4], p1 = pos[t * 4 + 1], p2 = pos[t * 4 + 2], p3 = pos[t * 4 + 3];
  float s2 = 0.f, r2 = 0.f;
  if (tid < 192) {                                  // 768 / 4
    const short4* sp = (const short4*)spart;
    const short4* y4 = (const short4*)Y;
    size_t base = (size_t)t * 192 + tid;
    float sx = 0.f, sy = 0.f, sz = 0.f, sw = 0.f;
#pragma unroll
    for (int e = 0; e < 4; ++e) {
      short4 v = sp[(size_t)e * T_TOK * 192 + base];
      sx += bf2f(v.x); sy += bf2f(v.y); sz += bf2f(v.z); sw += bf2f(v.w);
    }
    sx *= 0.125f; sy *= 0.125f; sz *= 0.125f; sw *= 0.125f;
    float rx = 0.f, ry = 0.f, rz = 0.f, rw = 0.f;
    int pp[4] = {p0, p1, p2, p3};
#pragma unroll
    for (int k = 0; k < 4; ++k) {
      short4 v = y4[(size_t)pp[k] * 192 + tid];
      rx += bf2f(v.x); ry += bf2f(v.y); rz += bf2f(v.z); rw += bf2f(v.w);
    }
    float4 o;
    o.x = sx + rx; o.y = sy + ry; o.z = sz + rz; o.w = sw + rw;
    ((float4*)out)[base] = o;
    s2 = sx * sx + sy * sy + sz * sz + sw * sw;
    r2 = rx * rx + ry * ry + rz * rz + rw * rw;
  }
  for (int o = 32; o > 0; o >>= 1) { s2 += __shfl_down(s2, o); r2 += __shfl_down(r2, o); }
  __shared__ float red[8];
  int wv = tid >> 6, lane = tid & 63;
  if (lane == 0) { red[wv] = s2; red[4 + wv] = r2; }
  __syncthreads();
  if (tid == 0) {
    float st = red[0] + red[1] + red[2] + red[3];
    float rt = red[4] + red[5] + red[6] + red[7];
    pnorm[t] = sqrtf(st);
    pnorm[T_TOK + t] = sqrtf(rt);
  }
}

__global__ __launch_bounds__(256) void finalize_kernel(const int* __restrict__ counts,
    const float* __restrict__ pent, const float* __restrict__ pnorm, float* __restrict__ o) {
  int tid = threadIdx.x;
  float es = 0.f, ss = 0.f, rs = 0.f;
  for (int i = tid; i < T_TOK; i += 256) {
    es += pent[i]; ss += pnorm[i]; rs += pnorm[T_TOK + i];
  }
  float vs = 0.f;
  if (tid < 32) { float d = (float)counts[tid] - 512.f; vs = d * d; }
  for (int off = 32; off > 0; off >>= 1) {
    es += __shfl_down(es, off); ss += __shfl_down(ss, off);
    rs += __shfl_down(rs, off); vs += __shfl_down(vs, off);
  }
  __shared__ float red[16];
  int wv = tid >> 6, lane = tid & 63;
  if (lane == 0) { red[wv] = es; red[4 + wv] = ss; red[8 + wv] = rs; red[12 + wv] = vs; }
  __syncthreads();
  if (tid == 0) {
    es = red[0] + red[1] + red[2] + red[3];
    ss = red[4] + red[5] + red[6] + red[7];
    rs = red[8] + red[9] + red[10] + red[11];
    vs = red[12] + red[13] + red[14] + red[15];
    o[0] = vs / 31.f;                     // load_balance_loss (ddof=1, mean=512 exact)
    o[1] = es / (float)T_TOK;             // router_entropy
    o[2] = fabsf(ss - rs) / (float)T_TOK; // balance_loss
  }
}

// ---------------------------------------------------------------------------
extern "C" void kernel_launch(void* const* d_in, const int* in_sizes, int n_in,
                              void* d_out, int out_size, void* d_ws, size_t ws_size,
                              hipStream_t stream) {
  const float* x   = (const float*)d_in[0];
  const float* swg = (const float*)d_in[1];
  const float* swu = (const float*)d_in[2];
  const float* swd = (const float*)d_in[3];
  const float* rw1 = (const float*)d_in[4];
  const float* rw2 = (const float*)d_in[5];
  const float* rdn = (const float*)d_in[6];
  const float* rup = (const float*)d_in[7];
  float* fout = (float*)d_out;

  // ---- workspace layout ----
  char* w = (char*)d_ws;
  size_t off = 0;
  auto take = [&](size_t bytes) { char* p = w + off; off = (off + bytes + 255) & ~(size_t)255; return p; };
  short* xbf   = (short*)take((size_t)T_TOK * DHID * 2);
  int*   sel   = (int*)  take((size_t)T_TOK * 4 * 4);
  float* w4    = (float*)take((size_t)T_TOK * 4 * 4);
  int*   pos   = (int*)  take((size_t)T_TOK * 4 * 4);
  int*   counts= (int*)  take(32 * 4);
  int*   cursor= (int*)  take(32 * 4);
  int*   meta  = (int*)  take(64 * 4);
  int*   tlist = (int*)  take((size_t)MAXROWS * 4);
  float* wslot = (float*)take((size_t)MAXROWS * 4);
  float* pent  = (float*)take((size_t)T_TOK * 4);
  float* pnorm = (float*)take((size_t)2 * T_TOK * 4);
  short* spart = (short*)take((size_t)4 * T_TOK * DHID * 2);   // 25.2 MB (bf16)
  char*  arena = w + off;

  // arena (phase-overlapped; LIFETIME ORDER MATTERS):
  // shared phase:  [wgT 28.3][wuT 28.3][wdT 28.3][Hsh 151]
  // routed phase:  [Y 31.5][w1T 75.5][w2T 75.5][Hr 62.9]
  // transpose_routed (w1T,w2T) must run AFTER the shared GEMMs.
  short* wgT = (short*)arena;
  short* wuT = wgT + (size_t)NE_S * F_S * DHID;
  short* wdT = wuT + (size_t)NE_S * F_S * DHID;
  short* Hsh = wdT + (size_t)NE_S * F_S * DHID;
  short* Y   = (short*)arena;                               // bf16
  short* w1T = (short*)(arena + (size_t)MAXROWS * DHID * 2 + 256);
  short* w2T = w1T + (size_t)NE_R * F_R * DHID;
  short* Hr  = w2T + (size_t)NE_R * F_R * DHID;

  // ---- setup / router ----
  prep_kernel<<<T_TOK, 64, 0, stream>>>(x, xbf, rdn, rup, sel, w4, pent,
                                        tlist, wslot, cursor);
  build_kernel<<<T_TOK / 256, 256, 0, stream>>>(sel, w4, counts, cursor,
                                                tlist, wslot, pos, meta);

  // ---- shared experts ----
  transpose_shared<<<10368, 256, 0, stream>>>(swg, swu, swd, wgT, wuT, wdT);
  gemm_k<0><<<dim3(F_S / 64, T_TOK / 128, NE_S), 256, 0, stream>>>(
      xbf, wgT, wuT, Hsh, nullptr, nullptr, nullptr,
      DHID, DHID, (long)F_S * DHID, (long)NE_S * F_S, 0, 0);
  gemm_k<2><<<dim3(DHID / 128, T_TOK / 128, NE_S / 2), 256, 0, stream>>>(
      Hsh, wdT, nullptr, spart, nullptr, nullptr, nullptr,
      F_S, NE_S * F_S, (long)DHID * F_S, DHID, (long)T_TOK * DHID, (long)F_S);

  // ---- routed experts (sparse, tile-compacted) ----
  transpose_routed<<<18432, 256, 0, stream>>>(rw1, rw2, w1T, w2T);
  gemm_k<1><<<dim3(F_R / 128, MAX_TILES, 1), 256, 0, stream>>>(
      xbf, w1T, nullptr, Hr, wslot, meta, tlist,
      DHID, DHID, (long)F_R * DHID, (long)F_R, 0, 0);
  gemm_k<3><<<dim3(DHID / 128, MAX_TILES, 1), 256, 0, stream>>>(
      Hr, w2T, nullptr, Y, nullptr, meta, tlist,
      F_R, F_R, (long)DHID * F_R, DHID, 0, 0);

  // ---- combine + scalars ----
  combine_kernel<<<T_TOK, 256, 0, stream>>>(spart, Y, pos, fout, pnorm);
  finalize_kernel<<<1, 256, 0, stream>>>(counts, pent, pnorm, fout + (size_t)T_TOK * DHID);
}